// Round 4
// baseline (762.944 us; speedup 1.0000x reference)
//
#include <hip/hip_runtime.h>
#include <hip/hip_bf16.h>
#include <stdint.h>

#define N_VOX 131072
#define KVOL  27
#define PPK   65536
#define CIN   64
#define COUT  64
#define TOT   (KVOL * PPK)         // 1769472 pairs
#define SORT_BLOCKS 864            // hist/scatter blocks, 2048 pairs each
#define GEMM_BLOCKS (KVOL * (PPK / 128))  // 13824
#define NB    512                  // buckets = hi-9 bits of key (256 rows each)

typedef __attribute__((ext_vector_type(8))) short short8;
typedef __attribute__((ext_vector_type(4))) float f32x4;

__device__ __forceinline__ void gl_lds16(const void* g, void* l) {
  __builtin_amdgcn_global_load_lds(
      (const __attribute__((address_space(1))) unsigned int*)g,
      (__attribute__((address_space(3))) unsigned int*)l,
      16, 0, 0);
}

__device__ __forceinline__ unsigned short f2bf(float f) {
  __hip_bfloat16 h = __float2bfloat16(f);
  return *reinterpret_cast<unsigned short*>(&h);
}

// ---------------- k1: fused cast + weight transpose + bucket histogram ----------------
// blocks [0,864): LDS-hist 2048 keys into 512 hi-buckets, write per-(bucket,block)
//   counts (NO global atomics). then 4096 cast blocks + 27 wt blocks.

__global__ __launch_bounds__(256) void prep_hist_kernel(
    const float* __restrict__ in, unsigned short* __restrict__ inb,
    const float* __restrict__ w, unsigned short* __restrict__ wt,
    const int* __restrict__ omap, int* __restrict__ counts, int do_sort) {
  int b = blockIdx.x;
  if (do_sort) {
    if (b < SORT_BLOCKS) {
      __shared__ unsigned int hist[NB];
      int tid = threadIdx.x;
      hist[tid] = 0; hist[tid + 256] = 0;
      __syncthreads();
      int e0 = (b * 256 + tid) * 8;
      int4 o0 = *(const int4*)(omap + e0);
      int4 o1 = *(const int4*)(omap + e0 + 4);
      atomicAdd(&hist[(unsigned)o0.x >> 8], 1u);
      atomicAdd(&hist[(unsigned)o0.y >> 8], 1u);
      atomicAdd(&hist[(unsigned)o0.z >> 8], 1u);
      atomicAdd(&hist[(unsigned)o0.w >> 8], 1u);
      atomicAdd(&hist[(unsigned)o1.x >> 8], 1u);
      atomicAdd(&hist[(unsigned)o1.y >> 8], 1u);
      atomicAdd(&hist[(unsigned)o1.z >> 8], 1u);
      atomicAdd(&hist[(unsigned)o1.w >> 8], 1u);
      __syncthreads();
      counts[(size_t)tid * SORT_BLOCKS + b] = (int)hist[tid];
      counts[(size_t)(tid + 256) * SORT_BLOCKS + b] = (int)hist[tid + 256];
      return;
    }
    b -= SORT_BLOCKS;
  }
  if (b < 4096) {
    int i = b * 256 + threadIdx.x;
    const float4* in4 = (const float4*)in;
    float4 f0 = in4[2 * i], f1 = in4[2 * i + 1];
    union { unsigned short u[8]; short8 v; } r;
    r.u[0] = f2bf(f0.x); r.u[1] = f2bf(f0.y); r.u[2] = f2bf(f0.z); r.u[3] = f2bf(f0.w);
    r.u[4] = f2bf(f1.x); r.u[5] = f2bf(f1.y); r.u[6] = f2bf(f1.z); r.u[7] = f2bf(f1.w);
    ((short8*)inb)[i] = r.v;
  } else {
    int k = b - 4096;
    const float* wk = w + k * CIN * COUT;
    unsigned short* wtk = wt + k * CIN * COUT;
    for (int idx = threadIdx.x; idx < CIN * COUT; idx += 256) {
      int c = idx >> 6, o = idx & 63;
      wtk[o * 64 + c] = f2bf(wk[idx]);
    }
  }
}

// ---------------- k2: per-bucket exclusive scan over the 864 block counts ----------------
// block b: blockbase[b][blk] = prefix of counts[b][*]; totals[b] = bucket total.
// 864 = 216 * 4: threads 0..215 own int4 chunks.

__global__ __launch_bounds__(256) void scan_blocks_kernel(
    const int* __restrict__ counts, int* __restrict__ blockbase,
    int* __restrict__ totals) {
  __shared__ int s[256];
  int b = blockIdx.x, t = threadIdx.x;
  const int* row = counts + (size_t)b * SORT_BLOCKS;
  int4 c = make_int4(0, 0, 0, 0);
  if (t < 216) c = *(const int4*)(row + t * 4);
  int sum = c.x + c.y + c.z + c.w;
  s[t] = sum; __syncthreads();
  for (int off = 1; off < 256; off <<= 1) {
    int v = (t >= off) ? s[t - off] : 0;
    __syncthreads();
    s[t] += v;
    __syncthreads();
  }
  int excl = s[t] - sum;
  int* brow = blockbase + (size_t)b * SORT_BLOCKS;
  if (t < 216) {
    brow[t * 4]     = excl;
    brow[t * 4 + 1] = excl + c.x;
    brow[t * 4 + 2] = excl + c.x + c.y;
    brow[t * 4 + 3] = excl + c.x + c.y + c.z;
  }
  if (t == 255) totals[b] = s[255];
}

// ---------------- k3: scan bucket totals -> global bucket slot bases ----------------

__global__ __launch_bounds__(NB) void base_kernel(const int* __restrict__ totals,
                                                  int* __restrict__ bbase) {
  __shared__ int s[NB];
  int t = threadIdx.x;
  int v = totals[t];
  s[t] = v; __syncthreads();
  for (int off = 1; off < NB; off <<= 1) {
    int x = (t >= off) ? s[t - off] : 0;
    __syncthreads();
    s[t] += x;
    __syncthreads();
  }
  bbase[t] = s[t] - v;
  if (t == NB - 1) bbase[NB] = s[NB - 1];   // == TOT
}

// ---------------- k4: deterministic scatter -> islot (coalesced) + lokey (1B) ----------------
// islot[e] = ((bbase[bk] + blockbase[bk][blk] + rank) << 8) | lo8.
// rank via LDS cursor: arbitrary within (bucket,block) but bijective -- exact.

__global__ __launch_bounds__(256) void scatter_kernel(
    const int* __restrict__ omap, const int* __restrict__ blockbase,
    const int* __restrict__ bbase, int* __restrict__ islot,
    unsigned char* __restrict__ lokey) {
  __shared__ unsigned int gb[NB];
  __shared__ unsigned int cur[NB];
  int b = blockIdx.x, tid = threadIdx.x;
  for (int i = tid; i < NB; i += 256) {
    gb[i] = (unsigned)(bbase[i] + blockbase[(size_t)i * SORT_BLOCKS + b]);
    cur[i] = 0;
  }
  __syncthreads();
  int e0 = (b * 256 + tid) * 8;
  int4 o0 = *(const int4*)(omap + e0);
  int4 o1 = *(const int4*)(omap + e0 + 4);
  unsigned int key[8] = {(unsigned)o0.x, (unsigned)o0.y, (unsigned)o0.z, (unsigned)o0.w,
                         (unsigned)o1.x, (unsigned)o1.y, (unsigned)o1.z, (unsigned)o1.w};
  int res[8];
#pragma unroll
  for (int i = 0; i < 8; i++) {
    unsigned int bk = key[i] >> 8;
    unsigned int r = atomicAdd(&cur[bk], 1u);
    unsigned int pos = gb[bk] + r;
    unsigned int lo = key[i] & 255u;
    res[i] = (int)((pos << 8) | lo);
    lokey[pos] = (unsigned char)lo;
  }
  *(int4*)(islot + e0)     = make_int4(res[0], res[1], res[2], res[3]);
  *(int4*)(islot + e0 + 4) = make_int4(res[4], res[5], res[6], res[7]);
}

// ---------------- k5: gather -> MFMA -> nt-store rows at bucket-sorted positions ----------------

__global__ __launch_bounds__(256) void spconv_store_kernel(
    const unsigned short* __restrict__ inb,   // [N][64] bf16
    const unsigned short* __restrict__ wt,    // [27][COUT][CIN] bf16
    const int* __restrict__ imap,
    const int* __restrict__ islot,            // packed (slot<<8)|lo
    unsigned short* __restrict__ contrib) {   // [TOT][64] bf16, bucket-sorted
  __shared__ __align__(16) char smem[24576];
  short* A_lds = (short*)smem;            // 16 KB: 128 pairs x 64 cin (fragment-major)
  short* B_lds = (short*)(smem + 16384);  //  8 KB: 64 cout x 64 cin
  short* C_sh  = (short*)smem;            // epilogue: [128][72] bf16
  __shared__ int perm_s[128];

  int bid = blockIdx.x;
  int k = bid >> 9;
  int pbase = (bid & 511) * 128;
  int tid = threadIdx.x;
  int wave = tid >> 6, lane = tid & 63;
  int m = lane & 15, q = lane >> 4;

  const int* imk = imap + k * PPK;
  const unsigned short* wtk = wt + k * 4096;

  if (tid < 128) perm_s[tid] = (int)(((unsigned)islot[k * PPK + pbase + tid]) >> 8);

#pragma unroll
  for (int i = 0; i < 2; i++) {
    int id = wave * 2 + i;
    int t = id >> 1, s = id & 1;
    const unsigned short* g = wtk + (t * 16 + m) * 64 + s * 32 + q * 8;
    gl_lds16(g, &B_lds[(t * 128 + s * 64) * 8]);
  }
#pragma unroll
  for (int j = 0; j < 2; j++) {
    int r = wave * 2 + j;
    int row = imk[pbase + r * 16 + m];
    const unsigned short* g0 = inb + row * 64 + q * 8;
    gl_lds16(g0,      &A_lds[(r * 128)      * 8]);
    gl_lds16(g0 + 32, &A_lds[(r * 128 + 64) * 8]);
  }
  __syncthreads();

  const short8* Af = (const short8*)A_lds;
  const short8* Bf = (const short8*)B_lds;

  short8 a[2][2], b[4][2];
#pragma unroll
  for (int r2 = 0; r2 < 2; r2++) {
    int r = wave * 2 + r2;
#pragma unroll
    for (int s = 0; s < 2; s++) a[r2][s] = Af[r * 128 + s * 64 + lane];
  }
#pragma unroll
  for (int t = 0; t < 4; t++)
#pragma unroll
    for (int s = 0; s < 2; s++) b[t][s] = Bf[t * 128 + s * 64 + lane];

  __syncthreads();   // frag reads done before LDS reuse for C

  f32x4 acc[2][4];
#pragma unroll
  for (int r2 = 0; r2 < 2; r2++)
#pragma unroll
    for (int t = 0; t < 4; t++) {
      f32x4 c = {0.f, 0.f, 0.f, 0.f};
      c = __builtin_amdgcn_mfma_f32_16x16x32_bf16(a[r2][0], b[t][0], c, 0, 0, 0);
      c = __builtin_amdgcn_mfma_f32_16x16x32_bf16(a[r2][1], b[t][1], c, 0, 0, 0);
      acc[r2][t] = c;
    }

  // C layout: row(pair) = q*4 + reg, col(cout) = t*16 + m
#pragma unroll
  for (int r2 = 0; r2 < 2; r2++) {
    int pl = (wave * 2 + r2) * 16 + q * 4;
#pragma unroll
    for (int t = 0; t < 4; t++)
#pragma unroll
      for (int reg = 0; reg < 4; reg++)
        C_sh[(pl + reg) * 72 + t * 16 + m] = (short)f2bf(acc[r2][t][reg]);
  }
  __syncthreads();

  // nontemporal full-line stores to bucket-sorted slots
#pragma unroll
  for (int i = 0; i < 4; i++) {
    int id = i * 256 + tid;
    int row = id >> 3, ch = (id & 7) * 8;
    short8 v = *(const short8*)&C_sh[row * 72 + ch];
    __builtin_nontemporal_store(v, (short8*)&contrib[(size_t)perm_s[row] * 64 + ch]);
  }
}

// ---------------- k6: bucket-granular LDS-accumulate reduce + bias ----------------
// one block per bucket (256 output rows); 64KB fp32 LDS accumulator; stream the
// contiguous contrib segment one row per wave-op (64 lanes = 64 channels,
// ds_add_f32 at 2-way bank = free), unroll 16 for MLP.

__global__ __launch_bounds__(256) void reduce_lds_kernel(
    const unsigned short* __restrict__ contrib,
    const unsigned char* __restrict__ lokey,
    const int* __restrict__ bbase,
    const float* __restrict__ bias,
    float* __restrict__ out) {
  __shared__ float acc[256 * 64];   // exactly 64 KB
  int tid = threadIdx.x;
  float4* a4 = (float4*)acc;
#pragma unroll
  for (int i = 0; i < 16; i++) a4[tid + i * 256] = make_float4(0.f, 0.f, 0.f, 0.f);
  __syncthreads();

  int b = blockIdx.x;
  int sb = bbase[b], se = bbase[b + 1];
  int w = tid >> 6, l = tid & 63;

  int s = sb + w;
  for (; s + 60 < se; s += 64) {
    unsigned int v[16]; unsigned int kk[16];
#pragma unroll
    for (int u = 0; u < 16; u++) {
      v[u]  = (unsigned int)__builtin_nontemporal_load(&contrib[(size_t)(s + 4 * u) * 64 + l]);
      kk[u] = (unsigned int)lokey[s + 4 * u];
    }
#pragma unroll
    for (int u = 0; u < 16; u++)
      atomicAdd(&acc[kk[u] * 64 + l], __uint_as_float(v[u] << 16));
  }
  for (; s < se; s += 4) {
    unsigned int v = (unsigned int)contrib[(size_t)s * 64 + l];
    unsigned int kk = (unsigned int)lokey[s];
    atomicAdd(&acc[kk * 64 + l], __uint_as_float(v << 16));
  }
  __syncthreads();

  // epilogue: 256 rows x 64 ch + bias, coalesced float4
  for (int j = tid; j < 4096; j += 256) {
    int row = j >> 4, c4 = (j & 15) * 4;
    float4 bb = *(const float4*)(bias + c4);
    float4 a = a4[j];
    float4 r = {a.x + bb.x, a.y + bb.y, a.z + bb.z, a.w + bb.w};
    *(float4*)(out + ((size_t)b * 256 + row) * 64 + c4) = r;
  }
}

// ---------------- fallback (atomic path) ----------------

__global__ __launch_bounds__(256) void init_out_kernel(float* __restrict__ out,
                                                       const float* __restrict__ bias) {
  int i = blockIdx.x * blockDim.x + threadIdx.x;
  float4 b = *(const float4*)(bias + ((i * 4) & 63));
  ((float4*)out)[i] = b;
}

__global__ __launch_bounds__(256) void spconv_atomic_kernel(
    const unsigned short* __restrict__ inb,
    const unsigned short* __restrict__ wt,
    const int* __restrict__ imap, const int* __restrict__ omap,
    float* __restrict__ out) {
  __shared__ __align__(16) short A_lds[128 * 64];
  __shared__ __align__(16) short B_lds[64 * 64];

  int bid = blockIdx.x;
  int k = bid >> 9;
  int pbase = (bid & 511) * 128;
  int tid = threadIdx.x;
  int wave = tid >> 6, lane = tid & 63;
  int m = lane & 15, q = lane >> 4;

  const int* imk = imap + k * PPK;
  const int* omk = omap + k * PPK;
  const unsigned short* wtk = wt + k * 4096;

#pragma unroll
  for (int i = 0; i < 2; i++) {
    int id = wave * 2 + i;
    int t = id >> 1, s = id & 1;
    const unsigned short* g = wtk + (t * 16 + m) * 64 + s * 32 + q * 8;
    gl_lds16(g, &B_lds[(t * 128 + s * 64) * 8]);
  }
#pragma unroll
  for (int j = 0; j < 2; j++) {
    int r = wave * 2 + j;
    int row = imk[pbase + r * 16 + m];
    const unsigned short* g0 = inb + row * 64 + q * 8;
    gl_lds16(g0,      &A_lds[(r * 128)      * 8]);
    gl_lds16(g0 + 32, &A_lds[(r * 128 + 64) * 8]);
  }
  __syncthreads();

  const short8* Af = (const short8*)A_lds;
  const short8* Bf = (const short8*)B_lds;
  short8 a[2][2], b[4][2];
#pragma unroll
  for (int r2 = 0; r2 < 2; r2++) {
    int r = wave * 2 + r2;
#pragma unroll
    for (int s = 0; s < 2; s++) a[r2][s] = Af[r * 128 + s * 64 + lane];
  }
#pragma unroll
  for (int t = 0; t < 4; t++)
#pragma unroll
    for (int s = 0; s < 2; s++) b[t][s] = Bf[t * 128 + s * 64 + lane];

  f32x4 acc[2][4];
#pragma unroll
  for (int r2 = 0; r2 < 2; r2++)
#pragma unroll
    for (int t = 0; t < 4; t++) {
      f32x4 c = {0.f, 0.f, 0.f, 0.f};
      c = __builtin_amdgcn_mfma_f32_16x16x32_bf16(a[r2][0], b[t][0], c, 0, 0, 0);
      c = __builtin_amdgcn_mfma_f32_16x16x32_bf16(a[r2][1], b[t][1], c, 0, 0, 0);
      acc[r2][t] = c;
    }

  int orow[2][4];
#pragma unroll
  for (int r2 = 0; r2 < 2; r2++) {
    int pr = pbase + (wave * 2 + r2) * 16 + q * 4;
#pragma unroll
    for (int reg = 0; reg < 4; reg++) orow[r2][reg] = omk[pr + reg];
  }
#pragma unroll
  for (int r2 = 0; r2 < 2; r2++)
#pragma unroll
    for (int t = 0; t < 4; t++)
#pragma unroll
      for (int reg = 0; reg < 4; reg++)
        atomicAdd(out + (size_t)orow[r2][reg] * 64 + t * 16 + m, acc[r2][t][reg]);
}

// ---------------- launch ----------------

extern "C" void kernel_launch(void* const* d_in, const int* in_sizes, int n_in,
                              void* d_out, int out_size, void* d_ws, size_t ws_size,
                              hipStream_t stream) {
  const float* in_feats = (const float*)d_in[0];
  const float* kern     = (const float*)d_in[1];
  const float* bias     = (const float*)d_in[2];
  const int*   imap     = (const int*)d_in[3];
  const int*   omap     = (const int*)d_in[4];
  float* out = (float*)d_out;

  char* ws = (char*)d_ws;
  size_t off = 0;
  auto alloc = [&](size_t bytes) { size_t o = off; off = (off + bytes + 255) & ~(size_t)255; return o; };

  size_t o_inb   = alloc((size_t)N_VOX * CIN * 2);        // 16.78 MB
  size_t o_wt    = alloc((size_t)KVOL * CIN * COUT * 2);  // 0.22 MB
  size_t o_cts   = alloc((size_t)NB * SORT_BLOCKS * 4);   // 1.77 MB
  size_t o_bb    = alloc((size_t)NB * SORT_BLOCKS * 4);   // 1.77 MB
  size_t o_tot   = alloc((size_t)NB * 4);                 // 2 KB
  size_t o_bbase = alloc((size_t)(NB + 1) * 4);           // 2 KB
  size_t o_islot = alloc((size_t)TOT * 4);                // 7.08 MB
  size_t o_lok   = alloc((size_t)TOT);                    // 1.77 MB
  size_t o_ctb   = alloc((size_t)TOT * 64 * 2);           // 226.5 MB
  size_t needed = off;

  unsigned short* inb = (unsigned short*)(ws + o_inb);
  unsigned short* wt  = (unsigned short*)(ws + o_wt);
  int* counts    = (int*)(ws + o_cts);
  int* blockbase = (int*)(ws + o_bb);
  int* totals    = (int*)(ws + o_tot);
  int* bbase     = (int*)(ws + o_bbase);
  int* islot     = (int*)(ws + o_islot);
  unsigned char* lokey = (unsigned char*)(ws + o_lok);
  unsigned short* ctb  = (unsigned short*)(ws + o_ctb);

  bool fast = (ws_size >= needed);

  if (fast) {
    prep_hist_kernel<<<SORT_BLOCKS + 4096 + KVOL, 256, 0, stream>>>(
        in_feats, inb, kern, wt, omap, counts, 1);
    scan_blocks_kernel<<<NB, 256, 0, stream>>>(counts, blockbase, totals);
    base_kernel<<<1, NB, 0, stream>>>(totals, bbase);
    scatter_kernel<<<SORT_BLOCKS, 256, 0, stream>>>(omap, blockbase, bbase, islot, lokey);
    spconv_store_kernel<<<GEMM_BLOCKS, 256, 0, stream>>>(inb, wt, imap, islot, ctb);
    reduce_lds_kernel<<<NB, 256, 0, stream>>>(ctb, lokey, bbase, bias, out);
  } else {
    prep_hist_kernel<<<4096 + KVOL, 256, 0, stream>>>(
        in_feats, inb, kern, wt, omap, nullptr, 0);
    init_out_kernel<<<(N_VOX * COUT / 4) / 256, 256, 0, stream>>>(out, bias);
    spconv_atomic_kernel<<<GEMM_BLOCKS, 256, 0, stream>>>(inb, wt, imap, omap, out);
  }
}